// Round 5
// baseline (137.110 us; speedup 1.0000x reference)
//
#include <hip/hip_runtime.h>
#include <hip/hip_bf16.h>
#include <math.h>

// Problem constants
#define NWL    296
#define FMD    74          // pooled feature dim
#define HEAD   64
#define EMBD   48
#define BATCH  2048
#define XCOLS  300
#define NPAIR  2701        // 74*73/2 upper-triangle pairs
#define NPAIR_P 3072       // padded; dummy pairs have wAT=0
#define KCH    768         // pairs per Sm chunk (4 chunks)
#define MR     8           // batch rows per fused block

// Workspace float offsets (uses ~424 KB of d_ws)
#define WS_CMR  0                          // [74][64] colsum-rowsum of wDI
#define WS_PAIR (FMD * HEAD)               // 4736: [NPAIR_P] u32 (4I | 4J<<16)
#define WS_WATT (WS_PAIR + NPAIR_P)        // 7808: [64][3072] fp16 wAT^T

typedef _Float16 f16x8 __attribute__((ext_vector_type(8)));
typedef float f32x4 __attribute__((ext_vector_type(4)));

__device__ __forceinline__ float eluf(float x) { return x > 0.f ? x : expm1f(x); }

// decode pair index k -> (I,J), I<J, row-major upper triangle
__device__ __forceinline__ void pair_decode(int k, int& I, int& J) {
  I = (int)((147.0f - sqrtf(21609.0f - 8.0f * (float)k)) * 0.5f);
  int base = (I * (147 - I)) >> 1;
  while (base > k) { I--; base = (I * (147 - I)) >> 1; }
  while (I < 72 && ((I + 1) * (146 - I)) / 2 <= k) { I++; base = (I * (147 - I)) >> 1; }
  J = I + 1 + (k - base);
}

// ---------------------------------------------------------------------------
// prep: one block per head h. Stage wDI[h], wNDI[h] to LDS coalesced, then:
// cmr[K][h] (folded DI weights), wATt[h][k] fp16 (antisym NDI weights /16,
// MFMA B-fragment row order), pair table (block 0).
// ---------------------------------------------------------------------------
__global__ __launch_bounds__(256) void fcr_prep_v5(
    const float* __restrict__ wDI,
    const float* __restrict__ wNDI,
    float* __restrict__ ws) {
  __shared__ float wdL[FMD * FMD];   // 5476 floats
  __shared__ float wnL[FMD * FMD];

  int t = threadIdx.x;
  int h = blockIdx.x;

  const float4* gd = (const float4*)(wDI + (size_t)h * FMD * FMD);
  const float4* gn = (const float4*)(wNDI + (size_t)h * FMD * FMD);
  for (int i = t; i < FMD * FMD / 4; i += 256) {   // 1369 float4
    ((float4*)wdL)[i] = gd[i];
    ((float4*)wnL)[i] = gn[i];
  }
  __syncthreads();

  // wATt[h][k] fp16
  _Float16* wATt = (_Float16*)(ws + WS_WATT);
  for (int k = t; k < NPAIR_P; k += 256) {
    float v = 0.f;
    if (k < NPAIR) {
      int I, J; pair_decode(k, I, J);
      v = (wnL[I * FMD + J] - wnL[J * FMD + I]) * 0.0625f;
    }
    wATt[(size_t)h * NPAIR_P + k] = (_Float16)v;
  }

  // cmr[K][h] = colsum - rowsum of wDI[h]
  if (t < FMD) {
    int K = t;
    float cs = 0.f, rs = 0.f;
    for (int I = 0; I < FMD; I++) {
      cs += wdL[I * FMD + K];
      rs += wdL[K * FMD + I];
    }
    ws[WS_CMR + K * 64 + h] = cs - rs;
  }

  // pair table (xs byte-ish indices: 4I | 4J<<16)
  if (h == 0) {
    unsigned* P = (unsigned*)(ws + WS_PAIR);
    for (int k = t; k < NPAIR_P; k += 256) {
      unsigned pb = 0;
      if (k < NPAIR) {
        int I, J; pair_decode(k, I, J);
        pb = (unsigned)(4 * I) | ((unsigned)(4 * J) << 16);
      }
      P[k] = pb;
    }
  }
}

// ---------------------------------------------------------------------------
// fused: block = 8 batch rows, FULL K range + entire tail MLP.
//   phase A: S[m][k]=sum_{4x4}(u-v)/(u+v+eps) -> Sm fp16 (A-frag rows)
//   phase B: mfma_f32_16x16x32_f16 vs global wATt (B-frag = 16B loads, L2-hot)
//   DI: separable fp32 VALU path (exact)
//   tail: elu -> fc(64->48)x2 -> concat -> fc1 -> l1 -> l2 -> sigmoid
// grid = 2048/8 = 256 blocks (1/CU). Static LDS ~59 KB.
// ---------------------------------------------------------------------------
__global__ __launch_bounds__(256) void fcr_fused_v5(
    const float* __restrict__ x,
    const float* __restrict__ ws,
    const float* __restrict__ bDI,
    const float* __restrict__ fcDI_w,
    const float* __restrict__ fcDI_b,
    const float* __restrict__ bNDI,
    const float* __restrict__ fcNDI_w,
    const float* __restrict__ fcNDI_b,
    const float* __restrict__ fc1_w,
    const float* __restrict__ fc1_b,
    const float* __restrict__ l1_w,
    const float* __restrict__ l1_b,
    const float* __restrict__ l2_w,
    const float* __restrict__ l2_b,
    float* __restrict__ out) {
  __shared__ float xs[MR][308];        // 9856 B (stride 308: 16B mult, 20 mod 32)
  __shared__ float xs4[MR][FMD];       // 2368 B
  __shared__ _Float16 Sm[MR][776];     // 12416 B (768 + 8 pad; stride 1552B)
  __shared__ _Float16 wDT[HEAD * EMBD];   // [h][o] fp16, 6144 B
  __shared__ _Float16 wNT[HEAD * EMBD];   // 6144 B
  __shared__ _Float16 w1T[96 * 48];       // [i][o] 9216 B
  __shared__ _Float16 wl1T[48 * 20];      // [j][o] 1920 B
  __shared__ float wl2s[20];
  __shared__ float bDs[HEAD], bNs[HEAD], bDe[EMBD], bNe[EMBD], b1[48], bl1s[20];
  __shared__ float bl2s;
  __shared__ float ehD[MR][68], ehN[MR][68];  // pad 68
  __shared__ float e2[MR][100];
  __shared__ float e3[MR][52];
  __shared__ float e4[MR][20];

  const unsigned* pairG = (const unsigned*)(ws + WS_PAIR);
  const _Float16* wATt = (const _Float16*)(ws + WS_WATT);
  const float* cmr = ws + WS_CMR;

  int t = threadIdx.x;
  int row0 = blockIdx.x * MR;

  // ---- stage: x rows (float4) + tail weights (fp16) + biases ----
  for (int i = t; i < MR * (NWL / 4); i += 256) {   // 592
    int r = i / (NWL / 4), c4 = i - r * (NWL / 4);
    *(float4*)&xs[r][4 * c4] = *(const float4*)(x + (size_t)(row0 + r) * XCOLS + 4 * c4);
  }
  for (int i = t; i < HEAD * EMBD; i += 256) {
    int o = i >> 6, hh = i & 63;               // fcDI_w[o][hh]
    wDT[hh * EMBD + o] = (_Float16)fcDI_w[i];
    wNT[hh * EMBD + o] = (_Float16)fcNDI_w[i];
  }
  for (int i = t; i < 48 * 96; i += 256) {
    int o = i / 96, j = i - o * 96;            // fc1_w[o][j]
    w1T[j * 48 + o] = (_Float16)fc1_w[i];
  }
  for (int i = t; i < 20 * 48; i += 256) {
    int o = i / 48, j = i - o * 48;            // l1_w[o][j]
    wl1T[j * 20 + o] = (_Float16)l1_w[i];
  }
  if (t < 20)   { wl2s[t] = l2_w[t]; bl1s[t] = l1_b[t]; }
  if (t < HEAD) { bDs[t] = bDI[t]; bNs[t] = bNDI[t]; }
  if (t < EMBD) { bDe[t] = fcDI_b[t]; bNe[t] = fcNDI_b[t]; }
  if (t < 48)   b1[t] = fc1_b[t];
  if (t == 0)   bl2s = l2_b[0];
  __syncthreads();

  // ---- 4-pool ----
  for (int i = t; i < MR * FMD; i += 256) {
    int r = i / FMD, K = i - r * FMD;
    xs4[r][K] = 0.25f * (xs[r][4*K] + xs[r][4*K+1] + xs[r][4*K+2] + xs[r][4*K+3]);
  }
  __syncthreads();

  // ---- DI path (fp32, exact): thread (hh, g) -> rows 2g, 2g+1 ----
  {
    int hh = t & 63, g = t >> 6;
    float d0 = 0.f, d1 = 0.f;
    for (int K = 0; K < FMD; K++) {
      float w = cmr[K * 64 + hh];
      d0 = fmaf(xs4[2*g][K],   w, d0);
      d1 = fmaf(xs4[2*g+1][K], w, d1);
    }
    ehD[2*g][hh]   = eluf(d0 + bDs[hh]);
    ehD[2*g+1][hh] = eluf(d1 + bDs[hh]);
  }

  // ---- NDI: phase A (ratio sums) + phase B (MFMA), 4 chunks of 768 ----
  int lane = t & 63;
  int wv   = t >> 6;
  int n_in = lane & 15;
  int quad = lane >> 4;
  int h    = wv * 16 + n_in;    // output head column
  int mA   = t & 7;             // phase-A row
  int kg   = t >> 3;            // phase-A k-group (0..31)

  f32x4 acc = {0.f, 0.f, 0.f, 0.f};

  for (int chunk = 0; chunk < NPAIR_P / KCH; chunk++) {
    int kbase = chunk * KCH;
    #pragma unroll 4
    for (int j = 0; j < KCH / 32; j++) {       // 24
      int kc = kg + 32 * j;
      unsigned pb = pairG[kbase + kc];
      int bI = pb & 0xFFFF, bJ = pb >> 16;
      float4 uv = *(const float4*)&xs[mA][bJ];
      float4 vv = *(const float4*)&xs[mA][bI];
      float u2[4] = { fmaf(2.f, uv.x, 1e-5f), fmaf(2.f, uv.y, 1e-5f),
                      fmaf(2.f, uv.z, 1e-5f), fmaf(2.f, uv.w, 1e-5f) };
      float u[4]  = { uv.x, uv.y, uv.z, uv.w };
      float v[4]  = { vv.x, vv.y, vv.z, vv.w };
      float s = 0.f;
      #pragma unroll
      for (int a = 0; a < 4; a++) {
        float va = v[a] + 1e-5f;
        #pragma unroll
        for (int b = 0; b < 4; b++)
          s = fmaf(u2[b], __builtin_amdgcn_rcpf(u[b] + va), s);
      }
      Sm[mA][kc] = (_Float16)(s - 16.f);
    }
    __syncthreads();

    // A rows 8..15 read duplicated rows (their D rows are discarded)
    #pragma unroll
    for (int c = 0; c < KCH / 32; c++) {       // 24 MFMA
      f16x8 aF = *(const f16x8*)&Sm[n_in & 7][c * 32 + quad * 8];
      f16x8 bF = *(const f16x8*)&wATt[(size_t)h * NPAIR_P + kbase + c * 32 + quad * 8];
      acc = __builtin_amdgcn_mfma_f32_16x16x32_f16(aF, bF, acc, 0, 0, 0);
    }
    __syncthreads();
  }

  // D[m][n]: n=lane&15, m=quad*4+r; only m<8 valid
  if (quad < 2) {
    #pragma unroll
    for (int r = 0; r < 4; r++) {
      int m = quad * 4 + r;
      ehN[m][h] = eluf(acc[r] + bNs[h]);
    }
  }
  __syncthreads();

  // ---- tail MLP on 8 rows ----
  for (int i = t; i < MR * 96; i += 256) {
    int r = i / 96, o = i - r * 96;
    int isN = o >= 48;
    int o2 = isN ? o - 48 : o;
    const _Float16* wb = isN ? wNT : wDT;
    const float* eb = isN ? &ehN[r][0] : &ehD[r][0];
    float s = isN ? bNe[o2] : bDe[o2];
    for (int hh = 0; hh < 64; hh++)
      s = fmaf(eb[hh], (float)wb[hh * EMBD + o2], s);
    e2[r][o] = eluf(s);
  }
  __syncthreads();

  for (int i = t; i < MR * 48; i += 256) {
    int r = i / 48, o = i - r * 48;
    float s = b1[o];
    for (int j = 0; j < 96; j++)
      s = fmaf(e2[r][j], (float)w1T[j * 48 + o], s);
    e3[r][o] = eluf(s);
  }
  __syncthreads();

  if (t < MR * 20) {
    int r = t / 20, o = t - r * 20;
    float s = bl1s[o];
    for (int j = 0; j < 48; j++)
      s = fmaf(e3[r][j], (float)wl1T[j * 20 + o], s);
    e4[r][o] = eluf(s);
  }
  __syncthreads();

  if (t < MR) {
    float s = bl2s;
    for (int j = 0; j < 20; j++)
      s = fmaf(e4[t][j], wl2s[j], s);
    out[row0 + t] = 1.f / (1.f + expf(-s));
  }
}

extern "C" void kernel_launch(void* const* d_in, const int* in_sizes, int n_in,
                              void* d_out, int out_size, void* d_ws, size_t ws_size,
                              hipStream_t stream) {
  const float* x      = (const float*)d_in[0];
  const float* wDI    = (const float*)d_in[1];
  const float* bDI    = (const float*)d_in[2];
  const float* fcDI_w = (const float*)d_in[3];
  const float* fcDI_b = (const float*)d_in[4];
  const float* wNDI   = (const float*)d_in[5];
  const float* bNDI   = (const float*)d_in[6];
  const float* fcNDI_w= (const float*)d_in[7];
  const float* fcNDI_b= (const float*)d_in[8];
  const float* fc1_w  = (const float*)d_in[9];
  const float* fc1_b  = (const float*)d_in[10];
  const float* l1_w   = (const float*)d_in[11];
  const float* l1_b   = (const float*)d_in[12];
  const float* l2_w   = (const float*)d_in[13];
  const float* l2_b   = (const float*)d_in[14];
  float* out = (float*)d_out;
  float* ws = (float*)d_ws;   // ~424 KB used

  fcr_prep_v5<<<HEAD, 256, 0, stream>>>(wDI, wNDI, ws);
  fcr_fused_v5<<<BATCH / MR, 256, 0, stream>>>(x, ws, bDI, fcDI_w, fcDI_b,
      bNDI, fcNDI_w, fcNDI_b, fc1_w, fc1_b, l1_w, l1_b, l2_w, l2_b, out);
}

// Round 6
// 127.337 us; speedup vs baseline: 1.0768x; 1.0768x over previous
//
#include <hip/hip_runtime.h>
#include <hip/hip_bf16.h>
#include <math.h>

// Problem constants
#define NWL    296
#define FMD    74          // pooled feature dim
#define HEAD   64
#define EMBD   48
#define BATCH  2048
#define XCOLS  300
#define NPAIR  2701        // 74*73/2 upper-triangle pairs
#define NPAIR_P 3072       // padded; dummy pairs have wAT=0
#define KSPLIT 4
#define SEGLEN (NPAIR_P / KSPLIT)  // 768 pairs per segment
#define MR     8           // batch rows per main/tail block

// Workspace float offsets (~2.4 MB of d_ws)
#define WS_CMR  0                          // [74][64] colsum-rowsum of wDI
#define WS_PAIR (FMD * HEAD)               // 4736: [NPAIR_P] u32 (4I | 4J<<16)
#define WS_WATT (WS_PAIR + NPAIR_P)        // 7808: [64][3072] fp16 wAT^T
#define WS_PNDI (WS_WATT + HEAD * NPAIR_P / 2)  // 106112: [KSPLIT][BATCH][64] NDI partials

typedef _Float16 f16x8 __attribute__((ext_vector_type(8)));
typedef float f32x4 __attribute__((ext_vector_type(4)));

__device__ __forceinline__ float eluf(float x) { return x > 0.f ? x : expm1f(x); }

// decode pair index k -> (I,J), I<J, row-major upper triangle
__device__ __forceinline__ void pair_decode(int k, int& I, int& J) {
  I = (int)((147.0f - sqrtf(21609.0f - 8.0f * (float)k)) * 0.5f);
  int base = (I * (147 - I)) >> 1;
  while (base > k) { I--; base = (I * (147 - I)) >> 1; }
  while (I < 72 && ((I + 1) * (146 - I)) / 2 <= k) { I++; base = (I * (147 - I)) >> 1; }
  J = I + 1 + (k - base);
}

// ---------------------------------------------------------------------------
// prep: one block per head h. Stage wDI[h], wNDI[h] to LDS coalesced, then:
// cmr[K][h] (folded DI weights), wATt[h][k] fp16 (antisym NDI weights /16,
// MFMA B-fragment row order), pair table (block 0).
// ---------------------------------------------------------------------------
__global__ __launch_bounds__(256) void fcr_prep_v6(
    const float* __restrict__ wDI,
    const float* __restrict__ wNDI,
    float* __restrict__ ws) {
  __shared__ float wdL[FMD * FMD];   // 5476 floats
  __shared__ float wnL[FMD * FMD];

  int t = threadIdx.x;
  int h = blockIdx.x;

  const float4* gd = (const float4*)(wDI + (size_t)h * FMD * FMD);
  const float4* gn = (const float4*)(wNDI + (size_t)h * FMD * FMD);
  for (int i = t; i < FMD * FMD / 4; i += 256) {   // 1369 float4
    ((float4*)wdL)[i] = gd[i];
    ((float4*)wnL)[i] = gn[i];
  }
  __syncthreads();

  _Float16* wATt = (_Float16*)(ws + WS_WATT);
  for (int k = t; k < NPAIR_P; k += 256) {
    float v = 0.f;
    if (k < NPAIR) {
      int I, J; pair_decode(k, I, J);
      v = (wnL[I * FMD + J] - wnL[J * FMD + I]) * 0.0625f;
    }
    wATt[(size_t)h * NPAIR_P + k] = (_Float16)v;
  }

  if (t < FMD) {   // cmr[K][h] = colsum - rowsum of wDI[h]
    int K = t;
    float cs = 0.f, rs = 0.f;
    for (int I = 0; I < FMD; I++) {
      cs += wdL[I * FMD + K];
      rs += wdL[K * FMD + I];
    }
    ws[WS_CMR + K * 64 + h] = cs - rs;
  }

  if (h == 0) {    // pair table (xs float-index offsets: 4I | 4J<<16)
    unsigned* P = (unsigned*)(ws + WS_PAIR);
    for (int k = t; k < NPAIR_P; k += 256) {
      unsigned pb = 0;
      if (k < NPAIR) {
        int I, J; pair_decode(k, I, J);
        pb = (unsigned)(4 * I) | ((unsigned)(4 * J) << 16);
      }
      P[k] = pb;
    }
  }
}

// ---------------------------------------------------------------------------
// main (NDI only): block = 8 batch rows x one 768-pair K-segment.
// Phase A: S[m][k] = sum_{4x4}(u-v)/(u+v+eps) -> Sm fp16 (whole segment, one
// barrier). Phase B: 24x mfma_f32_16x16x32_f16 vs global wATt (L2-hot).
// grid = (2048/8)*4 = 1024 blocks -> 4 blocks/CU (launch_bounds caps VGPR).
// LDS 25.3 KB.
// ---------------------------------------------------------------------------
__global__ __launch_bounds__(256, 4) void fcr_main_v6(
    const float* __restrict__ x,
    float* __restrict__ ws) {
  __shared__ float xs[MR][308];        // 9856 B; stride 308: 16B mult, 20 mod 32
  __shared__ _Float16 Sm[MR][776];     // 12416 B; 768 + 8 pad (stride 1552 B)
  __shared__ unsigned pairsL[SEGLEN];  // 3072 B

  const unsigned* pairG = (const unsigned*)(ws + WS_PAIR);
  const _Float16* wATt = (const _Float16*)(ws + WS_WATT);
  float* pNDI = ws + WS_PNDI;

  int t = threadIdx.x;
  int seg = blockIdx.x & (KSPLIT - 1);
  int row0 = (blockIdx.x >> 2) * MR;
  int k0 = seg * SEGLEN;

  for (int i = t; i < MR * (NWL / 4); i += 256) {   // 592 float4
    int r = i / (NWL / 4), c4 = i - r * (NWL / 4);
    *(float4*)&xs[r][4 * c4] = *(const float4*)(x + (size_t)(row0 + r) * XCOLS + 4 * c4);
  }
  for (int i = t; i < SEGLEN; i += 256) pairsL[i] = pairG[k0 + i];
  __syncthreads();

  // ---- phase A: 8 rows x 768 pairs, 24 pairs/thread ----
  int mA = t & 7;             // row
  int kg = t >> 3;            // k-group 0..31
  #pragma unroll 4
  for (int j = 0; j < SEGLEN / 32; j++) {       // 24
    int kc = kg + 32 * j;
    unsigned pb = pairsL[kc];
    int bI = pb & 0xFFFF, bJ = pb >> 16;
    float4 uv = *(const float4*)&xs[mA][bJ];
    float4 vv = *(const float4*)&xs[mA][bI];
    float u2[4] = { fmaf(2.f, uv.x, 1e-5f), fmaf(2.f, uv.y, 1e-5f),
                    fmaf(2.f, uv.z, 1e-5f), fmaf(2.f, uv.w, 1e-5f) };
    float u[4]  = { uv.x, uv.y, uv.z, uv.w };
    float v[4]  = { vv.x, vv.y, vv.z, vv.w };
    float s = 0.f;
    #pragma unroll
    for (int a = 0; a < 4; a++) {
      float va = v[a] + 1e-5f;
      #pragma unroll
      for (int b = 0; b < 4; b++)
        s = fmaf(u2[b], __builtin_amdgcn_rcpf(u[b] + va), s);
    }
    Sm[mA][kc] = (_Float16)(s - 16.f);
  }
  __syncthreads();

  // ---- phase B: MFMA; A rows 8..15 duplicate rows 0..7 (discarded) ----
  int lane = t & 63;
  int wv   = t >> 6;
  int n_in = lane & 15;
  int quad = lane >> 4;
  int h    = wv * 16 + n_in;
  f32x4 acc = {0.f, 0.f, 0.f, 0.f};
  #pragma unroll
  for (int c = 0; c < SEGLEN / 32; c++) {       // 24 MFMA
    f16x8 aF = *(const f16x8*)&Sm[n_in & 7][c * 32 + quad * 8];
    f16x8 bF = *(const f16x8*)&wATt[(size_t)h * NPAIR_P + k0 + c * 32 + quad * 8];
    acc = __builtin_amdgcn_mfma_f32_16x16x32_f16(aF, bF, acc, 0, 0, 0);
  }

  // D[m][n]: n = lane&15, m = quad*4 + r; only m < 8 valid
  if (quad < 2) {
    #pragma unroll
    for (int r = 0; r < 4; r++) {
      int m = quad * 4 + r;
      pNDI[((size_t)seg * BATCH + row0 + m) * 64 + h] = acc[r];
    }
  }
}

// ---------------------------------------------------------------------------
// tail: stage x, pool, DI einsum (separable, fp32 exact), reduce NDI
// partials, elu, fcDI/fcNDI (64->48), concat(96), fc1(96->48), l1(48->20),
// l2(20->1), sigmoid. Weights fp16, LDS-transposed. grid = 256 blocks.
// ---------------------------------------------------------------------------
__global__ __launch_bounds__(256) void fcr_tail_v6(
    const float* __restrict__ x,
    const float* __restrict__ ws,
    const float* __restrict__ bDI,
    const float* __restrict__ fcDI_w,
    const float* __restrict__ fcDI_b,
    const float* __restrict__ bNDI,
    const float* __restrict__ fcNDI_w,
    const float* __restrict__ fcNDI_b,
    const float* __restrict__ fc1_w,
    const float* __restrict__ fc1_b,
    const float* __restrict__ l1_w,
    const float* __restrict__ l1_b,
    const float* __restrict__ l2_w,
    const float* __restrict__ l2_b,
    float* __restrict__ out) {
  __shared__ float xs[MR][308];
  __shared__ float xs4[MR][FMD];
  __shared__ _Float16 wDT[HEAD * EMBD];   // [h][o]
  __shared__ _Float16 wNT[HEAD * EMBD];
  __shared__ _Float16 w1T[96 * 48];       // [i][o]
  __shared__ _Float16 wl1T[48 * 20];      // [j][o]
  __shared__ float wl2s[20];
  __shared__ float bDs[HEAD], bNs[HEAD], bDe[EMBD], bNe[EMBD], b1[48], bl1s[20];
  __shared__ float bl2s;
  __shared__ float ehD[MR][68], ehN[MR][68];
  __shared__ float e2[MR][100];
  __shared__ float e3[MR][52];
  __shared__ float e4[MR][20];

  const float* cmr  = ws + WS_CMR;
  const float* pNDI = ws + WS_PNDI;

  int t = threadIdx.x;
  int row0 = blockIdx.x * MR;

  for (int i = t; i < MR * (NWL / 4); i += 256) {
    int r = i / (NWL / 4), c4 = i - r * (NWL / 4);
    *(float4*)&xs[r][4 * c4] = *(const float4*)(x + (size_t)(row0 + r) * XCOLS + 4 * c4);
  }
  for (int i = t; i < HEAD * EMBD; i += 256) {
    int o = i >> 6, hh = i & 63;               // fcDI_w[o][hh]
    wDT[hh * EMBD + o] = (_Float16)fcDI_w[i];
    wNT[hh * EMBD + o] = (_Float16)fcNDI_w[i];
  }
  for (int i = t; i < 48 * 96; i += 256) {
    int o = i / 96, j = i - o * 96;            // fc1_w[o][j]
    w1T[j * 48 + o] = (_Float16)fc1_w[i];
  }
  for (int i = t; i < 20 * 48; i += 256) {
    int o = i / 48, j = i - o * 48;            // l1_w[o][j]
    wl1T[j * 20 + o] = (_Float16)l1_w[i];
  }
  if (t < 20)   { wl2s[t] = l2_w[t]; bl1s[t] = l1_b[t]; }
  if (t < HEAD) { bDs[t] = bDI[t]; bNs[t] = bNDI[t]; }
  if (t < EMBD) { bDe[t] = fcDI_b[t]; bNe[t] = fcNDI_b[t]; }
  if (t < 48)   b1[t] = fc1_b[t];
  if (t == 0)   bl2s = l2_b[0];
  __syncthreads();

  for (int i = t; i < MR * FMD; i += 256) {
    int r = i / FMD, K = i - r * FMD;
    xs4[r][K] = 0.25f * (xs[r][4*K] + xs[r][4*K+1] + xs[r][4*K+2] + xs[r][4*K+3]);
  }
  __syncthreads();

  // DI (fp32 exact): thread (hh, g) -> rows 2g, 2g+1
  {
    int hh = t & 63, g = t >> 6;
    float d0 = 0.f, d1 = 0.f;
    for (int K = 0; K < FMD; K++) {
      float w = cmr[K * 64 + hh];
      d0 = fmaf(xs4[2*g][K],   w, d0);
      d1 = fmaf(xs4[2*g+1][K], w, d1);
    }
    ehD[2*g][hh]   = eluf(d0 + bDs[hh]);
    ehD[2*g+1][hh] = eluf(d1 + bDs[hh]);
  }
  // NDI partial reduce + elu
  for (int i = t; i < MR * HEAD; i += 256) {
    int r = i >> 6, hh = i & 63;
    int row = row0 + r;
    float hN = bNs[hh];
    for (int s2 = 0; s2 < KSPLIT; s2++)
      hN += pNDI[((size_t)s2 * BATCH + row) * 64 + hh];
    ehN[r][hh] = eluf(hN);
  }
  __syncthreads();

  for (int i = t; i < MR * 96; i += 256) {
    int r = i / 96, o = i - r * 96;
    int isN = o >= 48;
    int o2 = isN ? o - 48 : o;
    const _Float16* wb = isN ? wNT : wDT;
    const float* eb = isN ? &ehN[r][0] : &ehD[r][0];
    float s = isN ? bNe[o2] : bDe[o2];
    for (int hh = 0; hh < 64; hh++)
      s = fmaf(eb[hh], (float)wb[hh * EMBD + o2], s);
    e2[r][o] = eluf(s);
  }
  __syncthreads();

  for (int i = t; i < MR * 48; i += 256) {
    int r = i / 48, o = i - r * 48;
    float s = b1[o];
    for (int j = 0; j < 96; j++)
      s = fmaf(e2[r][j], (float)w1T[j * 48 + o], s);
    e3[r][o] = eluf(s);
  }
  __syncthreads();

  if (t < MR * 20) {
    int r = t / 20, o = t - r * 20;
    float s = bl1s[o];
    for (int j = 0; j < 48; j++)
      s = fmaf(e3[r][j], (float)wl1T[j * 20 + o], s);
    e4[r][o] = eluf(s);
  }
  __syncthreads();

  if (t < MR) {
    float s = bl2s;
    for (int j = 0; j < 20; j++)
      s = fmaf(e4[t][j], wl2s[j], s);
    out[row0 + t] = 1.f / (1.f + expf(-s));
  }
}

extern "C" void kernel_launch(void* const* d_in, const int* in_sizes, int n_in,
                              void* d_out, int out_size, void* d_ws, size_t ws_size,
                              hipStream_t stream) {
  const float* x      = (const float*)d_in[0];
  const float* wDI    = (const float*)d_in[1];
  const float* bDI    = (const float*)d_in[2];
  const float* fcDI_w = (const float*)d_in[3];
  const float* fcDI_b = (const float*)d_in[4];
  const float* wNDI   = (const float*)d_in[5];
  const float* bNDI   = (const float*)d_in[6];
  const float* fcNDI_w= (const float*)d_in[7];
  const float* fcNDI_b= (const float*)d_in[8];
  const float* fc1_w  = (const float*)d_in[9];
  const float* fc1_b  = (const float*)d_in[10];
  const float* l1_w   = (const float*)d_in[11];
  const float* l1_b   = (const float*)d_in[12];
  const float* l2_w   = (const float*)d_in[13];
  const float* l2_b   = (const float*)d_in[14];
  float* out = (float*)d_out;
  float* ws = (float*)d_ws;   // ~2.4 MB used

  fcr_prep_v6<<<HEAD, 256, 0, stream>>>(wDI, wNDI, ws);
  fcr_main_v6<<<(BATCH / MR) * KSPLIT, 256, 0, stream>>>(x, ws);
  fcr_tail_v6<<<BATCH / MR, 256, 0, stream>>>(x, ws, bDI, fcDI_w, fcDI_b,
      bNDI, fcNDI_w, fcNDI_b, fc1_w, fc1_b, l1_w, l1_b, l2_w, l2_b, out);
}

// Round 7
// 127.016 us; speedup vs baseline: 1.0795x; 1.0025x over previous
//
#include <hip/hip_runtime.h>
#include <hip/hip_bf16.h>
#include <math.h>

// Problem constants
#define NWL    296
#define FMD    74          // pooled feature dim
#define HEAD   64
#define EMBD   48
#define BATCH  2048
#define XCOLS  300
#define NPAIR  2701        // 74*73/2 upper-triangle pairs
#define NPAIR_P 3072       // padded; dummy pairs have wAT=0
#define KSPLIT 8
#define SEGLEN (NPAIR_P / KSPLIT)  // 384 pairs per segment
#define MR     8           // batch rows per main/tail block

// Workspace float offsets (~4.6 MB of d_ws)
#define WS_CMR  0                          // [74][64] colsum-rowsum of wDI
#define WS_PAIR (FMD * HEAD)               // 4736: [NPAIR_P] u32 (4I | 4J<<16)
#define WS_WATT (WS_PAIR + NPAIR_P)        // 7808: [64][3072] fp16 wAT^T
#define WS_PNDI (WS_WATT + HEAD * NPAIR_P / 2)  // 106112: [KSPLIT][BATCH][64]

typedef _Float16 f16x8 __attribute__((ext_vector_type(8)));
typedef _Float16 f16x2 __attribute__((ext_vector_type(2)));
typedef float f32x4 __attribute__((ext_vector_type(4)));

__device__ __forceinline__ float eluf(float x) { return x > 0.f ? x : expm1f(x); }

// sum_{4x4} (u_b - v_a)/(u_b + v_a + eps) over two float4s, via rcp identity
__device__ __forceinline__ float ratio_sum16(float4 uv, float4 vv) {
  float u2[4] = { fmaf(2.f, uv.x, 1e-5f), fmaf(2.f, uv.y, 1e-5f),
                  fmaf(2.f, uv.z, 1e-5f), fmaf(2.f, uv.w, 1e-5f) };
  float u[4]  = { uv.x, uv.y, uv.z, uv.w };
  float v[4]  = { vv.x, vv.y, vv.z, vv.w };
  float s = 0.f;
  #pragma unroll
  for (int a = 0; a < 4; a++) {
    float va = v[a] + 1e-5f;
    #pragma unroll
    for (int b = 0; b < 4; b++)
      s = fmaf(u2[b], __builtin_amdgcn_rcpf(u[b] + va), s);
  }
  return s - 16.f;
}

// decode pair index k -> (I,J), I<J, row-major upper triangle
__device__ __forceinline__ void pair_decode(int k, int& I, int& J) {
  I = (int)((147.0f - sqrtf(21609.0f - 8.0f * (float)k)) * 0.5f);
  int base = (I * (147 - I)) >> 1;
  while (base > k) { I--; base = (I * (147 - I)) >> 1; }
  while (I < 72 && ((I + 1) * (146 - I)) / 2 <= k) { I++; base = (I * (147 - I)) >> 1; }
  J = I + 1 + (k - base);
}

// ---------------------------------------------------------------------------
// prep: one block per head h. Stage wDI[h], wNDI[h] to LDS coalesced, then:
// cmr[K][h], wATt[h][k] fp16 (antisym NDI weights /16, MFMA B-frag row
// order), pair table (block 0).
// ---------------------------------------------------------------------------
__global__ __launch_bounds__(256) void fcr_prep_v7(
    const float* __restrict__ wDI,
    const float* __restrict__ wNDI,
    float* __restrict__ ws) {
  __shared__ float wdL[FMD * FMD];   // 5476 floats
  __shared__ float wnL[FMD * FMD];

  int t = threadIdx.x;
  int h = blockIdx.x;

  const float4* gd = (const float4*)(wDI + (size_t)h * FMD * FMD);
  const float4* gn = (const float4*)(wNDI + (size_t)h * FMD * FMD);
  for (int i = t; i < FMD * FMD / 4; i += 256) {   // 1369 float4
    ((float4*)wdL)[i] = gd[i];
    ((float4*)wnL)[i] = gn[i];
  }
  __syncthreads();

  _Float16* wATt = (_Float16*)(ws + WS_WATT);
  for (int k = t; k < NPAIR_P; k += 256) {
    float v = 0.f;
    if (k < NPAIR) {
      int I, J; pair_decode(k, I, J);
      v = (wnL[I * FMD + J] - wnL[J * FMD + I]) * 0.0625f;
    }
    wATt[(size_t)h * NPAIR_P + k] = (_Float16)v;
  }

  if (t < FMD) {   // cmr[K][h] = colsum - rowsum of wDI[h]
    int K = t;
    float cs = 0.f, rs = 0.f;
    for (int I = 0; I < FMD; I++) {
      cs += wdL[I * FMD + K];
      rs += wdL[K * FMD + I];
    }
    ws[WS_CMR + K * 64 + h] = cs - rs;
  }

  if (h == 0) {    // pair table (xs float-index offsets: 4I | 4J<<16)
    unsigned* P = (unsigned*)(ws + WS_PAIR);
    for (int k = t; k < NPAIR_P; k += 256) {
      unsigned pb = 0;
      if (k < NPAIR) {
        int I, J; pair_decode(k, I, J);
        pb = (unsigned)(4 * I) | ((unsigned)(4 * J) << 16);
      }
      P[k] = pb;
    }
  }
}

// ---------------------------------------------------------------------------
// main (NDI only): block = 8 batch rows x one 384-pair K-segment.
// Phase A: S[m][k] -> Sm fp16 (packed 2-pair writes). Phase B: 12 MFMA vs
// global wATt (L2-hot). grid = 256*8 = 2048 blocks; LDS 17.7 KB;
// launch_bounds(256,6) -> ~6 blocks/CU (75% occupancy).
// ---------------------------------------------------------------------------
__global__ __launch_bounds__(256, 6) void fcr_main_v7(
    const float* __restrict__ x,
    float* __restrict__ ws) {
  __shared__ float xs[MR][308];        // 9856 B; stride 20 mod 32
  __shared__ _Float16 Sm[MR][392];     // 6272 B; 384 + 8 pad (stride 784 B)
  __shared__ unsigned pairsL[SEGLEN];  // 1536 B

  const unsigned* pairG = (const unsigned*)(ws + WS_PAIR);
  const _Float16* wATt = (const _Float16*)(ws + WS_WATT);
  float* pNDI = ws + WS_PNDI;

  int t = threadIdx.x;
  int seg = blockIdx.x & (KSPLIT - 1);
  int row0 = (blockIdx.x >> 3) * MR;
  int k0 = seg * SEGLEN;

  for (int i = t; i < MR * (NWL / 4); i += 256) {   // 592 float4
    int r = i / (NWL / 4), c4 = i - r * (NWL / 4);
    *(float4*)&xs[r][4 * c4] = *(const float4*)(x + (size_t)(row0 + r) * XCOLS + 4 * c4);
  }
  for (int i = t; i < SEGLEN; i += 256) pairsL[i] = pairG[k0 + i];
  __syncthreads();

  // ---- phase A: 8 rows x 384 pairs; 2 adjacent pairs per iter ----
  int mA = t & 7;             // row
  int kg = t >> 3;            // k-group 0..31
  #pragma unroll
  for (int j = 0; j < SEGLEN / 64; j++) {       // 6 iters, pairs (kc, kc+1)
    int kc = 2 * kg + 64 * j;
    uint2 pb2 = *(const uint2*)&pairsL[kc];
    int bI0 = pb2.x & 0xFFFF, bJ0 = pb2.x >> 16;
    int bI1 = pb2.y & 0xFFFF, bJ1 = pb2.y >> 16;
    float4 u0 = *(const float4*)&xs[mA][bJ0];
    float4 v0 = *(const float4*)&xs[mA][bI0];
    float4 u1 = *(const float4*)&xs[mA][bJ1];
    float4 v1 = *(const float4*)&xs[mA][bI1];
    float s0 = ratio_sum16(u0, v0);
    float s1 = ratio_sum16(u1, v1);
    f16x2 pk = { (_Float16)s0, (_Float16)s1 };
    *(f16x2*)&Sm[mA][kc] = pk;                  // 4B-aligned (kc even)
  }
  __syncthreads();

  // ---- phase B: MFMA; A rows 8..15 duplicate rows 0..7 (discarded) ----
  int lane = t & 63;
  int wv   = t >> 6;
  int n_in = lane & 15;
  int quad = lane >> 4;
  int h    = wv * 16 + n_in;
  f32x4 acc = {0.f, 0.f, 0.f, 0.f};
  #pragma unroll
  for (int c = 0; c < SEGLEN / 32; c++) {       // 12 MFMA
    f16x8 aF = *(const f16x8*)&Sm[n_in & 7][c * 32 + quad * 8];
    f16x8 bF = *(const f16x8*)&wATt[(size_t)h * NPAIR_P + k0 + c * 32 + quad * 8];
    acc = __builtin_amdgcn_mfma_f32_16x16x32_f16(aF, bF, acc, 0, 0, 0);
  }

  // D[m][n]: n = lane&15, m = quad*4 + r; only m < 8 valid
  if (quad < 2) {
    #pragma unroll
    for (int r = 0; r < 4; r++) {
      int m = quad * 4 + r;
      pNDI[((size_t)seg * BATCH + row0 + m) * 64 + h] = acc[r];
    }
  }
}

// ---------------------------------------------------------------------------
// tail: stage x, pool, DI einsum (separable, fp32 exact), reduce NDI
// partials, elu, fcDI/fcNDI (64->48), concat(96), fc1(96->48), l1(48->20),
// l2(20->1), sigmoid. Weights fp16, LDS-transposed. grid = 256 blocks.
// ---------------------------------------------------------------------------
__global__ __launch_bounds__(256) void fcr_tail_v7(
    const float* __restrict__ x,
    const float* __restrict__ ws,
    const float* __restrict__ bDI,
    const float* __restrict__ fcDI_w,
    const float* __restrict__ fcDI_b,
    const float* __restrict__ bNDI,
    const float* __restrict__ fcNDI_w,
    const float* __restrict__ fcNDI_b,
    const float* __restrict__ fc1_w,
    const float* __restrict__ fc1_b,
    const float* __restrict__ l1_w,
    const float* __restrict__ l1_b,
    const float* __restrict__ l2_w,
    const float* __restrict__ l2_b,
    float* __restrict__ out) {
  __shared__ float xs[MR][308];
  __shared__ float xs4[MR][FMD];
  __shared__ _Float16 wDT[HEAD * EMBD];   // [h][o]
  __shared__ _Float16 wNT[HEAD * EMBD];
  __shared__ _Float16 w1T[96 * 48];       // [i][o]
  __shared__ _Float16 wl1T[48 * 20];      // [j][o]
  __shared__ float wl2s[20];
  __shared__ float bDs[HEAD], bNs[HEAD], bDe[EMBD], bNe[EMBD], b1[48], bl1s[20];
  __shared__ float bl2s;
  __shared__ float ehD[MR][68], ehN[MR][68];
  __shared__ float e2[MR][100];
  __shared__ float e3[MR][52];
  __shared__ float e4[MR][20];

  const float* cmr  = ws + WS_CMR;
  const float* pNDI = ws + WS_PNDI;

  int t = threadIdx.x;
  int row0 = blockIdx.x * MR;

  for (int i = t; i < MR * (NWL / 4); i += 256) {
    int r = i / (NWL / 4), c4 = i - r * (NWL / 4);
    *(float4*)&xs[r][4 * c4] = *(const float4*)(x + (size_t)(row0 + r) * XCOLS + 4 * c4);
  }
  for (int i = t; i < HEAD * EMBD; i += 256) {
    int o = i >> 6, hh = i & 63;               // fcDI_w[o][hh]
    wDT[hh * EMBD + o] = (_Float16)fcDI_w[i];
    wNT[hh * EMBD + o] = (_Float16)fcNDI_w[i];
  }
  for (int i = t; i < 48 * 96; i += 256) {
    int o = i / 96, j = i - o * 96;            // fc1_w[o][j]
    w1T[j * 48 + o] = (_Float16)fc1_w[i];
  }
  for (int i = t; i < 20 * 48; i += 256) {
    int o = i / 48, j = i - o * 48;            // l1_w[o][j]
    wl1T[j * 20 + o] = (_Float16)l1_w[i];
  }
  if (t < 20)   { wl2s[t] = l2_w[t]; bl1s[t] = l1_b[t]; }
  if (t < HEAD) { bDs[t] = bDI[t]; bNs[t] = bNDI[t]; }
  if (t < EMBD) { bDe[t] = fcDI_b[t]; bNe[t] = fcNDI_b[t]; }
  if (t < 48)   b1[t] = fc1_b[t];
  if (t == 0)   bl2s = l2_b[0];
  __syncthreads();

  for (int i = t; i < MR * FMD; i += 256) {
    int r = i / FMD, K = i - r * FMD;
    xs4[r][K] = 0.25f * (xs[r][4*K] + xs[r][4*K+1] + xs[r][4*K+2] + xs[r][4*K+3]);
  }
  __syncthreads();

  // DI (fp32 exact): thread (hh, g) -> rows 2g, 2g+1
  {
    int hh = t & 63, g = t >> 6;
    float d0 = 0.f, d1 = 0.f;
    for (int K = 0; K < FMD; K++) {
      float w = cmr[K * 64 + hh];
      d0 = fmaf(xs4[2*g][K],   w, d0);
      d1 = fmaf(xs4[2*g+1][K], w, d1);
    }
    ehD[2*g][hh]   = eluf(d0 + bDs[hh]);
    ehD[2*g+1][hh] = eluf(d1 + bDs[hh]);
  }
  // NDI partial reduce + elu
  for (int i = t; i < MR * HEAD; i += 256) {
    int r = i >> 6, hh = i & 63;
    int row = row0 + r;
    float hN = bNs[hh];
    for (int s2 = 0; s2 < KSPLIT; s2++)
      hN += pNDI[((size_t)s2 * BATCH + row) * 64 + hh];
    ehN[r][hh] = eluf(hN);
  }
  __syncthreads();

  for (int i = t; i < MR * 96; i += 256) {
    int r = i / 96, o = i - r * 96;
    int isN = o >= 48;
    int o2 = isN ? o - 48 : o;
    const _Float16* wb = isN ? wNT : wDT;
    const float* eb = isN ? &ehN[r][0] : &ehD[r][0];
    float s = isN ? bNe[o2] : bDe[o2];
    for (int hh = 0; hh < 64; hh++)
      s = fmaf(eb[hh], (float)wb[hh * EMBD + o2], s);
    e2[r][o] = eluf(s);
  }
  __syncthreads();

  for (int i = t; i < MR * 48; i += 256) {
    int r = i / 48, o = i - r * 48;
    float s = b1[o];
    for (int j = 0; j < 96; j++)
      s = fmaf(e2[r][j], (float)w1T[j * 48 + o], s);
    e3[r][o] = eluf(s);
  }
  __syncthreads();

  if (t < MR * 20) {
    int r = t / 20, o = t - r * 20;
    float s = bl1s[o];
    for (int j = 0; j < 48; j++)
      s = fmaf(e3[r][j], (float)wl1T[j * 20 + o], s);
    e4[r][o] = eluf(s);
  }
  __syncthreads();

  if (t < MR) {
    float s = bl2s;
    for (int j = 0; j < 20; j++)
      s = fmaf(e4[t][j], wl2s[j], s);
    out[row0 + t] = 1.f / (1.f + expf(-s));
  }
}

extern "C" void kernel_launch(void* const* d_in, const int* in_sizes, int n_in,
                              void* d_out, int out_size, void* d_ws, size_t ws_size,
                              hipStream_t stream) {
  const float* x      = (const float*)d_in[0];
  const float* wDI    = (const float*)d_in[1];
  const float* bDI    = (const float*)d_in[2];
  const float* fcDI_w = (const float*)d_in[3];
  const float* fcDI_b = (const float*)d_in[4];
  const float* wNDI   = (const float*)d_in[5];
  const float* bNDI   = (const float*)d_in[6];
  const float* fcNDI_w= (const float*)d_in[7];
  const float* fcNDI_b= (const float*)d_in[8];
  const float* fc1_w  = (const float*)d_in[9];
  const float* fc1_b  = (const float*)d_in[10];
  const float* l1_w   = (const float*)d_in[11];
  const float* l1_b   = (const float*)d_in[12];
  const float* l2_w   = (const float*)d_in[13];
  const float* l2_b   = (const float*)d_in[14];
  float* out = (float*)d_out;
  float* ws = (float*)d_ws;   // ~4.6 MB used

  fcr_prep_v7<<<HEAD, 256, 0, stream>>>(wDI, wNDI, ws);
  fcr_main_v7<<<(BATCH / MR) * KSPLIT, 256, 0, stream>>>(x, ws);
  fcr_tail_v7<<<BATCH / MR, 256, 0, stream>>>(x, ws, bDI, fcDI_w, fcDI_b,
      bNDI, fcNDI_w, fcNDI_b, fc1_w, fc1_b, l1_w, l1_b, l2_w, l2_b, out);
}